// Round 10
// baseline (98.127 us; speedup 1.0000x reference)
//
#include <hip/hip_runtime.h>
#include <math.h>

#define BB 32
#define NN 4096
#define DD 768
#define CC 10
#define KK 16

typedef float v4f __attribute__((ext_vector_type(4)));

// ---------------------------------------------------------------------------
// Kernel 1: scores s[b,n] = dot(H[b,n,:], w_score) + b_score
// IDENTICAL to R9 (best: 89.6us) except ONE variable: plain float4 loads
// instead of __builtin_nontemporal_load — isolating the nt hint's effect on
// the 403 MB read stream. 512-thread blocks, one 64-lane wave per row,
// w_score in 3 float4 registers per lane.
// ---------------------------------------------------------------------------
__global__ __launch_bounds__(512) void score_kernel(
    const float* __restrict__ H, const float* __restrict__ w,
    const float* __restrict__ b_score, float* __restrict__ s) {
  const int wave = threadIdx.x >> 6;
  const int lane = threadIdx.x & 63;
  const long row = (long)blockIdx.x * 8 + wave;  // in [0, B*N)

  const v4f* __restrict__ w4 = (const v4f*)w;
  const v4f w0 = w4[lane];
  const v4f w1 = w4[lane + 64];
  const v4f w2 = w4[lane + 128];

  const v4f* __restrict__ Hrow = (const v4f*)H + row * 192;

  const v4f h0 = Hrow[lane];
  const v4f h1 = Hrow[lane + 64];
  const v4f h2 = Hrow[lane + 128];

  float acc = h0.x * w0.x + h0.y * w0.y + h0.z * w0.z + h0.w * w0.w;
  acc += h1.x * w1.x + h1.y * w1.y + h1.z * w1.z + h1.w * w1.w;
  acc += h2.x * w2.x + h2.y * w2.y + h2.z * w2.z + h2.w * w2.w;

#pragma unroll
  for (int off = 32; off >= 1; off >>= 1) acc += __shfl_xor(acc, off, 64);

  if (lane == 0) s[row] = acc + b_score[0];
}

// ---------------------------------------------------------------------------
// Kernel 2 (fused tail): R5/R9 VERBATIM. Per-batch top-16 (register-resident
// iterative argmax, 2 barriers/iter), A one-hot write, gather+mean+matvec.
// One block per batch. Tie-break: smaller index (lax.top_k).
// ---------------------------------------------------------------------------
__global__ __launch_bounds__(256) void tail_kernel(
    const float* __restrict__ s, const float* __restrict__ H,
    const float* __restrict__ Wc, const float* __restrict__ bc,
    float* __restrict__ logits, float* __restrict__ A) {
  const int b = blockIdx.x;
  const int t = threadIdx.x;
  const int wave = t >> 6;
  const int lane = t & 63;

  __shared__ float wv[4];
  __shared__ int wi[4];
  __shared__ int winners[KK];
  __shared__ float wp[4][CC];

  // Each thread owns 16 consecutive scores [t*16, t*16+16) in registers.
  float v[16];
  {
    const float4* sv4 = (const float4*)(s + (long)b * NN);
    float4 a0 = sv4[t * 4 + 0];
    float4 a1 = sv4[t * 4 + 1];
    float4 a2 = sv4[t * 4 + 2];
    float4 a3 = sv4[t * 4 + 3];
    v[0] = a0.x;  v[1] = a0.y;  v[2] = a0.z;  v[3] = a0.w;
    v[4] = a1.x;  v[5] = a1.y;  v[6] = a1.z;  v[7] = a1.w;
    v[8] = a2.x;  v[9] = a2.y;  v[10] = a2.z; v[11] = a2.w;
    v[12] = a3.x; v[13] = a3.y; v[14] = a3.z; v[15] = a3.w;
  }

  // Local running argmax (ascending scan keeps smallest index on ties).
  float lv = v[0];
  int li = t * 16;
#pragma unroll
  for (int j = 1; j < 16; ++j)
    if (v[j] > lv) { lv = v[j]; li = t * 16 + j; }

  for (int k = 0; k < KK; ++k) {
    float rv = lv;
    int ri = li;
#pragma unroll
    for (int off = 1; off < 64; off <<= 1) {
      float ov = __shfl_xor(rv, off, 64);
      int oi = __shfl_xor(ri, off, 64);
      if (ov > rv || (ov == rv && oi < ri)) { rv = ov; ri = oi; }
    }
    if (lane == 0) { wv[wave] = rv; wi[wave] = ri; }
    __syncthreads();

    float bv = wv[0];
    int bi = wi[0];
#pragma unroll
    for (int wq = 1; wq < 4; ++wq) {
      float ov = wv[wq];
      int oi = wi[wq];
      if (ov > bv || (ov == bv && oi < bi)) { bv = ov; bi = oi; }
    }
    if (t == 0) winners[k] = bi;

    if ((bi >> 4) == t) {
      const int slot = bi & 15;
#pragma unroll
      for (int j = 0; j < 16; ++j)
        if (j == slot) v[j] = -INFINITY;
      lv = -INFINITY;
      li = t * 16;
#pragma unroll
      for (int j = 0; j < 16; ++j)
        if (v[j] > lv) { lv = v[j]; li = t * 16 + j; }
    }
    __syncthreads();
  }

  // --- A one-hot write: 4096 floats per batch, float4 stores. ---
#pragma unroll
  for (int jj = 0; jj < 4; ++jj) {
    const int q = t + jj * 256;
    const int n0 = q * 4;
    float4 av = {0.f, 0.f, 0.f, 0.f};
#pragma unroll
    for (int k = 0; k < KK; ++k) {
      int d = winners[k] - n0;
      if (d == 0) av.x = 0.0625f;
      else if (d == 1) av.y = 0.0625f;
      else if (d == 2) av.z = 0.0625f;
      else if (d == 3) av.w = 0.0625f;
    }
    ((float4*)(A + (long)b * NN))[q] = av;
  }

  // --- Gather + mean + matvec fused: part[c] += (sum_k H[..])*(1/16)*Wc ---
  float part[CC];
#pragma unroll
  for (int c = 0; c < CC; ++c) part[c] = 0.f;
  for (int d = t; d < DD; d += 256) {
    float g = 0.f;
#pragma unroll
    for (int k = 0; k < KK; ++k)
      g += H[((long)b * NN + winners[k]) * DD + d];
    g *= (1.f / 16.f);
#pragma unroll
    for (int c = 0; c < CC; ++c) part[c] += g * Wc[d * CC + c];
  }
#pragma unroll
  for (int off = 32; off >= 1; off >>= 1) {
#pragma unroll
    for (int c = 0; c < CC; ++c) part[c] += __shfl_xor(part[c], off, 64);
  }
  if (lane == 0) {
#pragma unroll
    for (int c = 0; c < CC; ++c) wp[wave][c] = part[c];
  }
  __syncthreads();
  if (t < CC) {
    float r = wp[0][t] + wp[1][t] + wp[2][t] + wp[3][t];
    logits[b * CC + t] = r + bc[t];
  }
}

// ---------------------------------------------------------------------------
extern "C" void kernel_launch(void* const* d_in, const int* in_sizes, int n_in,
                              void* d_out, int out_size, void* d_ws, size_t ws_size,
                              hipStream_t stream) {
  const float* H = (const float*)d_in[0];
  const float* w_score = (const float*)d_in[1];
  const float* b_score = (const float*)d_in[2];
  const float* W_cls = (const float*)d_in[3];
  const float* b_cls = (const float*)d_in[4];

  float* out = (float*)d_out;
  float* logits = out;            // [B, C] = 320 floats
  float* A = out + BB * CC;       // [B, N, 1] = 131072 floats

  float* s = (float*)d_ws;        // B*N floats of scratch

  score_kernel<<<BB * NN / 8, 512, 0, stream>>>(H, w_score, b_score, s);
  tail_kernel<<<BB, 256, 0, stream>>>(s, H, W_cls, b_cls, logits, A);
}

// Round 11
// 90.333 us; speedup vs baseline: 1.0863x; 1.0863x over previous
//
#include <hip/hip_runtime.h>
#include <math.h>

#define BB 32
#define NN 4096
#define DD 768
#define CC 10
#define KK 16

typedef float v4f __attribute__((ext_vector_type(4)));

// ---------------------------------------------------------------------------
// Kernel 1: scores s[b,n] = dot(H[b,n,:], w_score) + b_score
// vs R9 (best, 89.6us): each wave now handles TWO consecutive rows, all 6
// non-temporal float4 loads issued up-front (no loop, still one-shot blocks).
// 512-thread block = 8 waves = 16 consecutive rows = 48KB contiguous.
// Lane 0 stores a float2 (one store per wave). Everything else identical.
// ---------------------------------------------------------------------------
__global__ __launch_bounds__(512) void score_kernel(
    const float* __restrict__ H, const float* __restrict__ w,
    const float* __restrict__ b_score, float* __restrict__ s) {
  const int wave = threadIdx.x >> 6;
  const int lane = threadIdx.x & 63;
  const long row0 = (long)blockIdx.x * 16 + wave * 2;  // even, in [0, B*N)

  const v4f* __restrict__ w4 = (const v4f*)w;
  const v4f w0 = w4[lane];
  const v4f w1 = w4[lane + 64];
  const v4f w2 = w4[lane + 128];

  const v4f* __restrict__ Ha = (const v4f*)H + row0 * 192;
  const v4f* __restrict__ Hb = Ha + 192;

  // All 6 loads issue before any dependent math.
  const v4f a0 = __builtin_nontemporal_load(Ha + lane);
  const v4f a1 = __builtin_nontemporal_load(Ha + lane + 64);
  const v4f a2 = __builtin_nontemporal_load(Ha + lane + 128);
  const v4f b0 = __builtin_nontemporal_load(Hb + lane);
  const v4f b1 = __builtin_nontemporal_load(Hb + lane + 64);
  const v4f b2 = __builtin_nontemporal_load(Hb + lane + 128);

  float accA = a0.x * w0.x + a0.y * w0.y + a0.z * w0.z + a0.w * w0.w;
  accA += a1.x * w1.x + a1.y * w1.y + a1.z * w1.z + a1.w * w1.w;
  accA += a2.x * w2.x + a2.y * w2.y + a2.z * w2.z + a2.w * w2.w;

  float accB = b0.x * w0.x + b0.y * w0.y + b0.z * w0.z + b0.w * w0.w;
  accB += b1.x * w1.x + b1.y * w1.y + b1.z * w1.z + b1.w * w1.w;
  accB += b2.x * w2.x + b2.y * w2.y + b2.z * w2.z + b2.w * w2.w;

#pragma unroll
  for (int off = 32; off >= 1; off >>= 1) {
    accA += __shfl_xor(accA, off, 64);
    accB += __shfl_xor(accB, off, 64);
  }

  if (lane == 0) {
    float2 o = {accA + b_score[0], accB + b_score[0]};
    *(float2*)(s + row0) = o;
  }
}

// ---------------------------------------------------------------------------
// Kernel 2 (fused tail): R5/R9 VERBATIM. Per-batch top-16 (register-resident
// iterative argmax, 2 barriers/iter), A one-hot write, gather+mean+matvec.
// One block per batch. Tie-break: smaller index (lax.top_k).
// ---------------------------------------------------------------------------
__global__ __launch_bounds__(256) void tail_kernel(
    const float* __restrict__ s, const float* __restrict__ H,
    const float* __restrict__ Wc, const float* __restrict__ bc,
    float* __restrict__ logits, float* __restrict__ A) {
  const int b = blockIdx.x;
  const int t = threadIdx.x;
  const int wave = t >> 6;
  const int lane = t & 63;

  __shared__ float wv[4];
  __shared__ int wi[4];
  __shared__ int winners[KK];
  __shared__ float wp[4][CC];

  // Each thread owns 16 consecutive scores [t*16, t*16+16) in registers.
  float v[16];
  {
    const float4* sv4 = (const float4*)(s + (long)b * NN);
    float4 a0 = sv4[t * 4 + 0];
    float4 a1 = sv4[t * 4 + 1];
    float4 a2 = sv4[t * 4 + 2];
    float4 a3 = sv4[t * 4 + 3];
    v[0] = a0.x;  v[1] = a0.y;  v[2] = a0.z;  v[3] = a0.w;
    v[4] = a1.x;  v[5] = a1.y;  v[6] = a1.z;  v[7] = a1.w;
    v[8] = a2.x;  v[9] = a2.y;  v[10] = a2.z; v[11] = a2.w;
    v[12] = a3.x; v[13] = a3.y; v[14] = a3.z; v[15] = a3.w;
  }

  // Local running argmax (ascending scan keeps smallest index on ties).
  float lv = v[0];
  int li = t * 16;
#pragma unroll
  for (int j = 1; j < 16; ++j)
    if (v[j] > lv) { lv = v[j]; li = t * 16 + j; }

  for (int k = 0; k < KK; ++k) {
    float rv = lv;
    int ri = li;
#pragma unroll
    for (int off = 1; off < 64; off <<= 1) {
      float ov = __shfl_xor(rv, off, 64);
      int oi = __shfl_xor(ri, off, 64);
      if (ov > rv || (ov == rv && oi < ri)) { rv = ov; ri = oi; }
    }
    if (lane == 0) { wv[wave] = rv; wi[wave] = ri; }
    __syncthreads();

    float bv = wv[0];
    int bi = wi[0];
#pragma unroll
    for (int wq = 1; wq < 4; ++wq) {
      float ov = wv[wq];
      int oi = wi[wq];
      if (ov > bv || (ov == bv && oi < bi)) { bv = ov; bi = oi; }
    }
    if (t == 0) winners[k] = bi;

    if ((bi >> 4) == t) {
      const int slot = bi & 15;
#pragma unroll
      for (int j = 0; j < 16; ++j)
        if (j == slot) v[j] = -INFINITY;
      lv = -INFINITY;
      li = t * 16;
#pragma unroll
      for (int j = 0; j < 16; ++j)
        if (v[j] > lv) { lv = v[j]; li = t * 16 + j; }
    }
    __syncthreads();
  }

  // --- A one-hot write: 4096 floats per batch, float4 stores. ---
#pragma unroll
  for (int jj = 0; jj < 4; ++jj) {
    const int q = t + jj * 256;
    const int n0 = q * 4;
    float4 av = {0.f, 0.f, 0.f, 0.f};
#pragma unroll
    for (int k = 0; k < KK; ++k) {
      int d = winners[k] - n0;
      if (d == 0) av.x = 0.0625f;
      else if (d == 1) av.y = 0.0625f;
      else if (d == 2) av.z = 0.0625f;
      else if (d == 3) av.w = 0.0625f;
    }
    ((float4*)(A + (long)b * NN))[q] = av;
  }

  // --- Gather + mean + matvec fused: part[c] += (sum_k H[..])*(1/16)*Wc ---
  float part[CC];
#pragma unroll
  for (int c = 0; c < CC; ++c) part[c] = 0.f;
  for (int d = t; d < DD; d += 256) {
    float g = 0.f;
#pragma unroll
    for (int k = 0; k < KK; ++k)
      g += H[((long)b * NN + winners[k]) * DD + d];
    g *= (1.f / 16.f);
#pragma unroll
    for (int c = 0; c < CC; ++c) part[c] += g * Wc[d * CC + c];
  }
#pragma unroll
  for (int off = 32; off >= 1; off >>= 1) {
#pragma unroll
    for (int c = 0; c < CC; ++c) part[c] += __shfl_xor(part[c], off, 64);
  }
  if (lane == 0) {
#pragma unroll
    for (int c = 0; c < CC; ++c) wp[wave][c] = part[c];
  }
  __syncthreads();
  if (t < CC) {
    float r = wp[0][t] + wp[1][t] + wp[2][t] + wp[3][t];
    logits[b * CC + t] = r + bc[t];
  }
}

// ---------------------------------------------------------------------------
extern "C" void kernel_launch(void* const* d_in, const int* in_sizes, int n_in,
                              void* d_out, int out_size, void* d_ws, size_t ws_size,
                              hipStream_t stream) {
  const float* H = (const float*)d_in[0];
  const float* w_score = (const float*)d_in[1];
  const float* b_score = (const float*)d_in[2];
  const float* W_cls = (const float*)d_in[3];
  const float* b_cls = (const float*)d_in[4];

  float* out = (float*)d_out;
  float* logits = out;            // [B, C] = 320 floats
  float* A = out + BB * CC;       // [B, N, 1] = 131072 floats

  float* s = (float*)d_ws;        // B*N floats of scratch

  score_kernel<<<BB * NN / 16, 512, 0, stream>>>(H, w_score, b_score, s);
  tail_kernel<<<BB, 256, 0, stream>>>(s, H, W_cls, b_cls, logits, A);
}

// Round 12
// 89.308 us; speedup vs baseline: 1.0987x; 1.0115x over previous
//
#include <hip/hip_runtime.h>
#include <math.h>

#define BB 32
#define NN 4096
#define DD 768
#define CC 10
#define KK 16

typedef float v4f __attribute__((ext_vector_type(4)));

// ---------------------------------------------------------------------------
// FINAL (R9 configuration, best measured: 89.6us).
// Kernel 1: scores s[b,n] = dot(H[b,n,:], w_score) + b_score
// One 64-lane wave per row, one-shot blocks (512 thr = 8 waves = 8 rows).
// w_score in 3 float4 registers per lane (no LDS, no barrier); H read with
// non-temporal float4 loads (read-once stream; isolated +8.5us win in R10).
// Structure survey: wave-ILP variants, multi-row loops, persistent grids,
// block-size changes, producer-consumer fusion all neutral or worse (R3-R11).
// ---------------------------------------------------------------------------
__global__ __launch_bounds__(512) void score_kernel(
    const float* __restrict__ H, const float* __restrict__ w,
    const float* __restrict__ b_score, float* __restrict__ s) {
  const int wave = threadIdx.x >> 6;
  const int lane = threadIdx.x & 63;
  const long row = (long)blockIdx.x * 8 + wave;  // in [0, B*N)

  const v4f* __restrict__ w4 = (const v4f*)w;
  const v4f w0 = w4[lane];
  const v4f w1 = w4[lane + 64];
  const v4f w2 = w4[lane + 128];

  const v4f* __restrict__ Hrow = (const v4f*)H + row * 192;

  const v4f h0 = __builtin_nontemporal_load(Hrow + lane);
  const v4f h1 = __builtin_nontemporal_load(Hrow + lane + 64);
  const v4f h2 = __builtin_nontemporal_load(Hrow + lane + 128);

  float acc = h0.x * w0.x + h0.y * w0.y + h0.z * w0.z + h0.w * w0.w;
  acc += h1.x * w1.x + h1.y * w1.y + h1.z * w1.z + h1.w * w1.w;
  acc += h2.x * w2.x + h2.y * w2.y + h2.z * w2.z + h2.w * w2.w;

#pragma unroll
  for (int off = 32; off >= 1; off >>= 1) acc += __shfl_xor(acc, off, 64);

  if (lane == 0) s[row] = acc + b_score[0];
}

// ---------------------------------------------------------------------------
// Kernel 2 (fused tail): per-batch top-16 (register-resident iterative
// argmax, 2 barriers/iter), A one-hot write, gather+mean+matvec fused.
// One block per batch. Tie-break: smaller index (matches lax.top_k).
// ---------------------------------------------------------------------------
__global__ __launch_bounds__(256) void tail_kernel(
    const float* __restrict__ s, const float* __restrict__ H,
    const float* __restrict__ Wc, const float* __restrict__ bc,
    float* __restrict__ logits, float* __restrict__ A) {
  const int b = blockIdx.x;
  const int t = threadIdx.x;
  const int wave = t >> 6;
  const int lane = t & 63;

  __shared__ float wv[4];
  __shared__ int wi[4];
  __shared__ int winners[KK];
  __shared__ float wp[4][CC];

  // Each thread owns 16 consecutive scores [t*16, t*16+16) in registers.
  float v[16];
  {
    const float4* sv4 = (const float4*)(s + (long)b * NN);
    float4 a0 = sv4[t * 4 + 0];
    float4 a1 = sv4[t * 4 + 1];
    float4 a2 = sv4[t * 4 + 2];
    float4 a3 = sv4[t * 4 + 3];
    v[0] = a0.x;  v[1] = a0.y;  v[2] = a0.z;  v[3] = a0.w;
    v[4] = a1.x;  v[5] = a1.y;  v[6] = a1.z;  v[7] = a1.w;
    v[8] = a2.x;  v[9] = a2.y;  v[10] = a2.z; v[11] = a2.w;
    v[12] = a3.x; v[13] = a3.y; v[14] = a3.z; v[15] = a3.w;
  }

  // Local running argmax (ascending scan keeps smallest index on ties).
  float lv = v[0];
  int li = t * 16;
#pragma unroll
  for (int j = 1; j < 16; ++j)
    if (v[j] > lv) { lv = v[j]; li = t * 16 + j; }

  for (int k = 0; k < KK; ++k) {
    float rv = lv;
    int ri = li;
#pragma unroll
    for (int off = 1; off < 64; off <<= 1) {
      float ov = __shfl_xor(rv, off, 64);
      int oi = __shfl_xor(ri, off, 64);
      if (ov > rv || (ov == rv && oi < ri)) { rv = ov; ri = oi; }
    }
    if (lane == 0) { wv[wave] = rv; wi[wave] = ri; }
    __syncthreads();

    float bv = wv[0];
    int bi = wi[0];
#pragma unroll
    for (int wq = 1; wq < 4; ++wq) {
      float ov = wv[wq];
      int oi = wi[wq];
      if (ov > bv || (ov == bv && oi < bi)) { bv = ov; bi = oi; }
    }
    if (t == 0) winners[k] = bi;

    if ((bi >> 4) == t) {
      const int slot = bi & 15;
#pragma unroll
      for (int j = 0; j < 16; ++j)
        if (j == slot) v[j] = -INFINITY;
      lv = -INFINITY;
      li = t * 16;
#pragma unroll
      for (int j = 0; j < 16; ++j)
        if (v[j] > lv) { lv = v[j]; li = t * 16 + j; }
    }
    __syncthreads();
  }

  // --- A one-hot write: 4096 floats per batch, float4 stores. ---
#pragma unroll
  for (int jj = 0; jj < 4; ++jj) {
    const int q = t + jj * 256;
    const int n0 = q * 4;
    float4 av = {0.f, 0.f, 0.f, 0.f};
#pragma unroll
    for (int k = 0; k < KK; ++k) {
      int d = winners[k] - n0;
      if (d == 0) av.x = 0.0625f;
      else if (d == 1) av.y = 0.0625f;
      else if (d == 2) av.z = 0.0625f;
      else if (d == 3) av.w = 0.0625f;
    }
    ((float4*)(A + (long)b * NN))[q] = av;
  }

  // --- Gather + mean + matvec fused: part[c] += (sum_k H[..])*(1/16)*Wc ---
  float part[CC];
#pragma unroll
  for (int c = 0; c < CC; ++c) part[c] = 0.f;
  for (int d = t; d < DD; d += 256) {
    float g = 0.f;
#pragma unroll
    for (int k = 0; k < KK; ++k)
      g += H[((long)b * NN + winners[k]) * DD + d];
    g *= (1.f / 16.f);
#pragma unroll
    for (int c = 0; c < CC; ++c) part[c] += g * Wc[d * CC + c];
  }
#pragma unroll
  for (int off = 32; off >= 1; off >>= 1) {
#pragma unroll
    for (int c = 0; c < CC; ++c) part[c] += __shfl_xor(part[c], off, 64);
  }
  if (lane == 0) {
#pragma unroll
    for (int c = 0; c < CC; ++c) wp[wave][c] = part[c];
  }
  __syncthreads();
  if (t < CC) {
    float r = wp[0][t] + wp[1][t] + wp[2][t] + wp[3][t];
    logits[b * CC + t] = r + bc[t];
  }
}

// ---------------------------------------------------------------------------
extern "C" void kernel_launch(void* const* d_in, const int* in_sizes, int n_in,
                              void* d_out, int out_size, void* d_ws, size_t ws_size,
                              hipStream_t stream) {
  const float* H = (const float*)d_in[0];
  const float* w_score = (const float*)d_in[1];
  const float* b_score = (const float*)d_in[2];
  const float* W_cls = (const float*)d_in[3];
  const float* b_cls = (const float*)d_in[4];

  float* out = (float*)d_out;
  float* logits = out;            // [B, C] = 320 floats
  float* A = out + BB * CC;       // [B, N, 1] = 131072 floats

  float* s = (float*)d_ws;        // B*N floats of scratch

  score_kernel<<<BB * NN / 8, 512, 0, stream>>>(H, w_score, b_score, s);
  tail_kernel<<<BB, 256, 0, stream>>>(s, H, W_cls, b_cls, logits, A);
}